// Round 14
// baseline (88.905 us; speedup 1.0000x reference)
//
#include <hip/hip_runtime.h>

#define WAVE 64
#define WPB 2     // waves per block in seg_stats
#define CAP 48    // max segment-window size per normalize block

// DPP-fused butterfly stage (VALU pipe). ctrl must be a literal.
template <int CTRL>
__device__ __forceinline__ float dpp_f(float x) {
    int xi = __builtin_bit_cast(int, x);
    int r  = __builtin_amdgcn_update_dpp(xi, xi, CTRL, 0xF, 0xF, false);
    return __builtin_bit_cast(float, r);
}
#define DPP_XOR1 0xB1   // quad_perm [1,0,3,2]
#define DPP_XOR2 0x4E   // quad_perm [2,3,0,1]
#define DPP_XOR4 0x141  // row_half_mirror
#define DPP_XOR8 0x140  // row_mirror

__device__ __forceinline__ unsigned div3u(unsigned n) {
    return (unsigned)(((unsigned long long)n * 0xAAAAAAABull) >> 33);
}

// idx may be int32 (JAX default) or int64 (x64 enabled).
__global__ void detect_idx64(const unsigned int* __restrict__ w32, long long N,
                             int* __restrict__ flag) {
    long long base = (N / 2) | 1LL;
    long long stride = ((N / 2) / 64) & ~1LL;
    if (stride < 2) stride = 2;
    long long p = base + (long long)threadIdx.x * stride;
    unsigned int v = (p < N) ? w32[p] : 0u;
    unsigned long long nz = __ballot(v != 0u);
    if (threadIdx.x == 0) *flag = (nz == 0ULL) ? 1 : 0;   // 1 -> int64
}

__device__ __forceinline__ int load_idx(const void* __restrict__ p,
                                        long long i, int is64) {
    return is64 ? (int)((const long long*)p)[i] : ((const int*)p)[i];
}

// start[t] = lower_bound(idx, t), one binary search per boundary.
__global__ void find_bounds_bs(const void* __restrict__ idxp,
                               const int* __restrict__ flag,
                               int* __restrict__ start,
                               long long N, int S) {
    const int t = blockIdx.x * blockDim.x + threadIdx.x;
    if (t > S) return;
    const int is64 = *flag;
    long long lo = 0, hi = N;
    while (lo < hi) {
        long long mid = (lo + hi) >> 1;
        if (load_idx(idxp, mid, is64) < t) lo = mid + 1; else hi = mid;
    }
    start[t] = (int)lo;
}

// STATS ONLY (R12 body minus the store phase): one wave per segment, both
// lane-iterations peeled so all 8 float4 loads issue up front; DPP+shfl
// butterfly; writes 20 B/segment (center+inv, diam). No store drain in the
// wave critical path; leaves pos hot in L3 for the normalize pass.
__global__ __launch_bounds__(WPB * WAVE)
void seg_stats(const float* __restrict__ pos,
               const float* __restrict__ w,
               const int* __restrict__ start,
               float4* __restrict__ sseg,
               float* __restrict__ diam_out,
               int S) {
    const int s = blockIdx.x * WPB + (threadIdx.x >> 6);
    if (s >= S) return;
    const int lane = threadIdx.x & 63;

    const int lo = start[s], hi = start[s + 1];
    const int g0 = lo >> 2, g1 = (hi + 3) >> 2;       // 4-point groups

    const float4* __restrict__ pos4 = (const float4*)pos;
    const float4* __restrict__ w4   = (const float4*)w;

    const int ga = g0 + lane;
    const int gb = ga + WAVE;
    const bool va = ga < g1, vb = gb < g1;
    const bool anyb = __any(vb);

    float4 a0 = {0,0,0,0}, a1 = {0,0,0,0}, a2 = {0,0,0,0}, aw = {0,0,0,0};
    float4 b0 = {0,0,0,0}, b1 = {0,0,0,0}, b2 = {0,0,0,0}, bw = {0,0,0,0};
    if (va) {
        a0 = pos4[3LL * ga]; a1 = pos4[3LL * ga + 1]; a2 = pos4[3LL * ga + 2];
        aw = w4[ga];
    }
    if (vb) {
        b0 = pos4[3LL * gb]; b1 = pos4[3LL * gb + 1]; b2 = pos4[3LL * gb + 2];
        bw = w4[gb];
    }

    float mnx = INFINITY,  mny = INFINITY,  mnz = INFINITY;
    float mxx = -INFINITY, mxy = -INFINITY, mxz = -INFINITY;
    float sw = 0.f, swx = 0.f, swy = 0.f, swz = 0.f;

    #define PROC(PI, X, Y, Z, WV)                                        \
    {                                                                    \
        bool in = ((PI) >= lo) & ((PI) < hi);                            \
        float xv = (X), yv = (Y), zv = (Z);                              \
        float wv = in ? (WV) : 0.f;                                      \
        mnx = fminf(mnx, in ? xv :  INFINITY);                           \
        mxx = fmaxf(mxx, in ? xv : -INFINITY);                           \
        mny = fminf(mny, in ? yv :  INFINITY);                           \
        mxy = fmaxf(mxy, in ? yv : -INFINITY);                           \
        mnz = fminf(mnz, in ? zv :  INFINITY);                           \
        mxz = fmaxf(mxz, in ? zv : -INFINITY);                           \
        sw += wv;                                                        \
        swx = fmaf(wv, xv, swx);                                         \
        swy = fmaf(wv, yv, swy);                                         \
        swz = fmaf(wv, zv, swz);                                         \
    }
    #define PROC_GROUP(G, R0, R1, R2, RW)                                \
    {                                                                    \
        const int p = (G) << 2;                                          \
        PROC(p + 0, R0.x, R0.y, R0.z, RW.x)                              \
        PROC(p + 1, R0.w, R1.x, R1.y, RW.y)                              \
        PROC(p + 2, R1.z, R1.w, R2.x, RW.z)                              \
        PROC(p + 3, R2.y, R2.z, R2.w, RW.w)                              \
    }

    PROC_GROUP(ga, a0, a1, a2, aw)
    if (anyb) PROC_GROUP(gb, b0, b1, b2, bw)

    // Pathological tail (segment > 512 points): never taken for this data.
    for (int g = g0 + 2 * WAVE + lane; g < g1; g += WAVE) {
        float4 c0 = pos4[3LL * g], c1 = pos4[3LL * g + 1], c2 = pos4[3LL * g + 2];
        float4 cw = w4[g];
        PROC_GROUP(g, c0, c1, c2, cw)
    }
    #undef PROC_GROUP
    #undef PROC

    #define ALLV(STAGEOP)                                \
        mnx = fminf(mnx, STAGEOP(mnx));                  \
        mny = fminf(mny, STAGEOP(mny));                  \
        mnz = fminf(mnz, STAGEOP(mnz));                  \
        mxx = fmaxf(mxx, STAGEOP(mxx));                  \
        mxy = fmaxf(mxy, STAGEOP(mxy));                  \
        mxz = fmaxf(mxz, STAGEOP(mxz));                  \
        sw  += STAGEOP(sw);                              \
        swx += STAGEOP(swx);                             \
        swy += STAGEOP(swy);                             \
        swz += STAGEOP(swz);
    #define ST_X1(v)  dpp_f<DPP_XOR1>(v)
    #define ST_X2(v)  dpp_f<DPP_XOR2>(v)
    #define ST_X4(v)  dpp_f<DPP_XOR4>(v)
    #define ST_X8(v)  dpp_f<DPP_XOR8>(v)
    #define ST_X16(v) __shfl_xor((v), 16)
    #define ST_X32(v) __shfl_xor((v), 32)
    ALLV(ST_X1) ALLV(ST_X2) ALLV(ST_X4) ALLV(ST_X8) ALLV(ST_X16) ALLV(ST_X32)
    #undef ST_X1
    #undef ST_X2
    #undef ST_X4
    #undef ST_X8
    #undef ST_X16
    #undef ST_X32
    #undef ALLV

    if (lane == 0) {
        const float diam = fmaxf(mxx - mnx, fmaxf(mxy - mny, mxz - mnz));
        const float wsafe = (sw == 0.f) ? 1.f : sw;
        sseg[s] = make_float4(swx / wsafe, swy / wsafe, swz / wsafe,
                              1.f / (diam + 0.01f));
        diam_out[s] = diam;
    }
}

// PURE STREAMING MAP: one thread per output float4 quad. Per-block segment
// window from start[] (thread-0 binary search + parallel window load into
// LDS); per-quad only 2 candidate points -> 2 cheap slot lookups. Dense
// float4 read (L3-hot from seg_stats) and dense float4 write.
__global__ __launch_bounds__(256)
void normalize_dense(const float* __restrict__ pos,
                     const int* __restrict__ start,
                     const float4* __restrict__ sseg,
                     float* __restrict__ out,
                     long long nF, int S) {
    const long long nQ = nF >> 2;
    const long long f  = (long long)blockIdx.x * 256 + threadIdx.x;

    __shared__ int    sLo_sh, nb_sh, ovf_sh;
    __shared__ int    sb[CAP];
    __shared__ float4 sg[CAP + 1];

    // Block's point range [ptA, ptB] (inclusive).
    const long long fblk0 = (long long)blockIdx.x * 256 * 4;
    long long fblk1 = fblk0 + 256 * 4;
    if (fblk1 > nF) fblk1 = nF;
    if (fblk0 >= nF) return;
    const unsigned ptA = div3u((unsigned)fblk0);
    const unsigned ptB = div3u((unsigned)(fblk1 - 1));

    if (threadIdx.x == 0) {
        // sLo = largest s in [0,S] with start[s] <= ptA  (start[0]=0).
        int lo = 0, hi = S + 1;
        while (lo + 1 < hi) {
            int mid = (lo + hi) >> 1;
            if ((unsigned)start[mid] <= ptA) lo = mid; else hi = mid;
        }
        sLo_sh = lo;
    }
    __syncthreads();
    const int sLo = sLo_sh;

    if (threadIdx.x < CAP) {
        int j = sLo + 1 + threadIdx.x;
        int b = (j <= S) ? start[j] : 0x7FFFFFFF;
        sb[threadIdx.x] = b;
        bool in = (j <= S) && ((unsigned)b <= ptB);
        unsigned long long m = __ballot(in);
        if (threadIdx.x == 0) {
            int cnt = __popcll(m);
            nb_sh  = cnt;
            ovf_sh = (cnt >= CAP) ? 1 : 0;   // window overflow -> fallback
        }
    }
    __syncthreads();
    const int nb = nb_sh;
    if (threadIdx.x <= nb && threadIdx.x <= CAP) {
        int j = sLo + threadIdx.x;
        sg[threadIdx.x] = (j < S) ? sseg[j] : make_float4(0.f, 0.f, 0.f, 0.f);
    }
    __syncthreads();

    if (f >= nQ) {
        // Tail floats (nF % 4): handled by the first threads past the quads.
        const long long r0 = nQ << 2;
        const long long Fi = r0 + (f - nQ);
        if (f == nQ && Fi < nF) {
            for (long long q = Fi; q < nF; ++q) {
                unsigned pt = div3u((unsigned)q);
                int k = (int)((unsigned)q - 3u * pt);
                int sl = 0;
                for (int j = 0; j < nb; ++j) sl += (pt >= (unsigned)sb[j]);
                float4 g = sg[sl];
                float ctr = (k == 0) ? g.x : ((k == 1) ? g.y : g.z);
                out[q] = (pos[q] - ctr) * g.w;
            }
        }
        return;
    }

    const float4 q = ((const float4*)pos)[f];
    const unsigned Fi0 = (unsigned)(f << 2);
    const unsigned ptL = div3u(Fi0);
    const unsigned ptH = ptL + 1;            // quad spans exactly pts ptL,ptL+1

    int slL, slH;
    if (!ovf_sh) {
        slL = 0;
        #pragma unroll 8
        for (int j = 0; j < nb; ++j) slL += (ptL >= (unsigned)sb[j]);
        slH = slL + ((slL < nb) && (ptH >= (unsigned)sb[slL]) ? 1 : 0);
    } else {
        // Never-taken-in-practice fallback: per-point global binary search.
        int lo = 0, hi = S + 1;
        while (lo + 1 < hi) {
            int mid = (lo + hi) >> 1;
            if ((unsigned)start[mid] <= ptL) lo = mid; else hi = mid;
        }
        slL = lo - sLo; slH = slL;
        if ((unsigned)start[(lo + 1 <= S) ? lo + 1 : S] <= ptH && lo + 1 <= S)
            slH = slL + 1;
    }
    const float4 gL = sg[slL];
    const float4 gH = sg[slH];

    float4 r;
    {
        // component c belongs to ptL while Fi0+c < 3*ptH, else ptH
        const unsigned lim = 3u * ptH;
        #pragma unroll
        for (int c = 0; c < 4; ++c) {
            const unsigned Fi = Fi0 + (unsigned)c;
            const bool hiPt = (Fi >= lim);
            const float4 g = hiPt ? gH : gL;
            const unsigned pt = hiPt ? ptH : ptL;
            const int k = (int)(Fi - 3u * pt);
            const float ctr = (k == 0) ? g.x : ((k == 1) ? g.y : g.z);
            const float v = (c == 0) ? q.x : (c == 1) ? q.y : (c == 2) ? q.z : q.w;
            ((float*)&r)[c] = (v - ctr) * g.w;
        }
    }
    ((float4*)out)[f] = r;
}

extern "C" void kernel_launch(void* const* d_in, const int* in_sizes, int n_in,
                              void* d_out, int out_size, void* d_ws, size_t ws_size,
                              hipStream_t stream) {
    const float* pos  = (const float*)d_in[0];
    const void*  idxp = d_in[1];
    const float* w    = (const float*)d_in[2];

    const long long nF = (long long)in_sizes[0];        // 3N
    const long long N  = nF / 3;                        // 8388608
    const int S = out_size - in_sizes[0];               // 32768

    float* out = (float*)d_out;
    float* diam_out = out + nF;                         // tail of d_out

    // ws: [flag 4B pad256][start (S+1) ints, pad256][sseg S float4]
    int* flag  = (int*)d_ws;
    int* start = (int*)((char*)d_ws + 256);
    size_t seg_off = (256 + (size_t)(S + 1) * 4 + 255) & ~(size_t)255;
    float4* sseg = (float4*)((char*)d_ws + seg_off);

    detect_idx64<<<1, 64, 0, stream>>>((const unsigned int*)idxp, N, flag);

    find_bounds_bs<<<(S + 1 + 63) / 64, 64, 0, stream>>>(idxp, flag, start, N, S);

    seg_stats<<<(S + WPB - 1) / WPB, WPB * WAVE, 0, stream>>>(
        pos, w, start, sseg, diam_out, S);

    const long long nQ = (nF + 3) >> 2;
    normalize_dense<<<(int)((nQ + 255) / 256), 256, 0, stream>>>(
        pos, start, sseg, out, nF, S);
}

// Round 15
// 57.738 us; speedup vs baseline: 1.5398x; 1.5398x over previous
//
#include <hip/hip_runtime.h>

#define WAVE 64
#define WPB 2    // waves per block (128-thread blocks: finer launch granularity)

// idx may be int32 (JAX default) or int64 (x64 enabled). Detection: odd 32-bit
// words in the upper half are high words of values < 2^31 under int64 layout
// (all zero); under int32 layout they are sorted values ~S/2 (nonzero).
__global__ void detect_idx64(const unsigned int* __restrict__ w32, long long N,
                             int* __restrict__ flag) {
    long long base = (N / 2) | 1LL;
    long long stride = ((N / 2) / 64) & ~1LL;
    if (stride < 2) stride = 2;
    long long p = base + (long long)threadIdx.x * stride;
    unsigned int v = (p < N) ? w32[p] : 0u;
    unsigned long long nz = __ballot(v != 0u);
    if (threadIdx.x == 0) *flag = (nz == 0ULL) ? 1 : 0;   // 1 -> int64
}

__device__ __forceinline__ int load_idx(const void* __restrict__ p,
                                        long long i, int is64) {
    return is64 ? (int)((const long long*)p)[i] : ((const int*)p)[i];
}

// One independent binary search per boundary: start[t] = lower_bound(idx, t).
// 64 independent 23-probe chains per wave; top tree levels are L2/L3-hot.
// Touches ~4 MB of idx lines instead of streaming all 34-67 MB.
__global__ void find_bounds_bs(const void* __restrict__ idxp,
                               const int* __restrict__ flag,
                               int* __restrict__ start,
                               long long N, int S) {
    const int t = blockIdx.x * blockDim.x + threadIdx.x;
    if (t > S) return;
    const int is64 = *flag;
    long long lo = 0, hi = N;
    while (lo < hi) {
        long long mid = (lo + hi) >> 1;
        if (load_idx(idxp, mid, is64) < t) lo = mid + 1; else hi = mid;
    }
    start[t] = (int)lo;
}

// One wave per segment (R5 body, verbatim; best measured). Segment <= 512
// points (<=2 lane-iterations) in the expected data; both iterations peeled
// statically so all 8 float4 loads issue before any dependent use, and the
// SAME registers feed the normalize phase (no second memory round-trip).
__global__ __launch_bounds__(WPB * WAVE)
void seg_norm(const float* __restrict__ pos,
              const float* __restrict__ w,
              const int* __restrict__ start,
              float* __restrict__ out,
              float* __restrict__ diam_out,
              int S) {
    const int s = blockIdx.x * WPB + (threadIdx.x >> 6);
    if (s >= S) return;
    const int lane = threadIdx.x & 63;

    const int lo = start[s], hi = start[s + 1];
    const int g0 = lo >> 2, g1 = (hi + 3) >> 2;       // 4-point groups

    const float4* __restrict__ pos4 = (const float4*)pos;
    const float4* __restrict__ w4   = (const float4*)w;

    const int ga = g0 + lane;          // iteration 0 group
    const int gb = ga + WAVE;          // iteration 1 group
    const bool va = ga < g1, vb = gb < g1;

    float4 a0 = {0,0,0,0}, a1 = {0,0,0,0}, a2 = {0,0,0,0}, aw = {0,0,0,0};
    float4 b0 = {0,0,0,0}, b1 = {0,0,0,0}, b2 = {0,0,0,0}, bw = {0,0,0,0};
    if (va) {
        a0 = pos4[3LL * ga]; a1 = pos4[3LL * ga + 1]; a2 = pos4[3LL * ga + 2];
        aw = w4[ga];
    }
    if (vb) {
        b0 = pos4[3LL * gb]; b1 = pos4[3LL * gb + 1]; b2 = pos4[3LL * gb + 2];
        bw = w4[gb];
    }

    float mnx = INFINITY,  mny = INFINITY,  mnz = INFINITY;
    float mxx = -INFINITY, mxy = -INFINITY, mxz = -INFINITY;
    float sw = 0.f, swx = 0.f, swy = 0.f, swz = 0.f;

    // p+0: (r0.x,r0.y,r0.z) w.x | p+1: (r0.w,r1.x,r1.y) w.y
    // p+2: (r1.z,r1.w,r2.x) w.z | p+3: (r2.y,r2.z,r2.w) w.w
    #define PROC(PI, X, Y, Z, WV)                                        \
    {                                                                    \
        bool in = ((PI) >= lo) & ((PI) < hi);                            \
        float xv = (X), yv = (Y), zv = (Z);                              \
        float wv = in ? (WV) : 0.f;                                      \
        mnx = fminf(mnx, in ? xv :  INFINITY);                           \
        mxx = fmaxf(mxx, in ? xv : -INFINITY);                           \
        mny = fminf(mny, in ? yv :  INFINITY);                           \
        mxy = fmaxf(mxy, in ? yv : -INFINITY);                           \
        mnz = fminf(mnz, in ? zv :  INFINITY);                           \
        mxz = fmaxf(mxz, in ? zv : -INFINITY);                           \
        sw += wv;                                                        \
        swx = fmaf(wv, xv, swx);                                         \
        swy = fmaf(wv, yv, swy);                                         \
        swz = fmaf(wv, zv, swz);                                         \
    }
    #define PROC_GROUP(G, R0, R1, R2, RW)                                \
    {                                                                    \
        const int p = (G) << 2;                                          \
        PROC(p + 0, R0.x, R0.y, R0.z, RW.x)                              \
        PROC(p + 1, R0.w, R1.x, R1.y, RW.y)                              \
        PROC(p + 2, R1.z, R1.w, R2.x, RW.z)                              \
        PROC(p + 3, R2.y, R2.z, R2.w, RW.w)                              \
    }

    PROC_GROUP(ga, a0, a1, a2, aw)
    PROC_GROUP(gb, b0, b1, b2, bw)

    // Pathological tail (segment > 512 points): never taken for this data.
    for (int g = g0 + 2 * WAVE + lane; g < g1; g += WAVE) {
        float4 c0 = pos4[3LL * g], c1 = pos4[3LL * g + 1], c2 = pos4[3LL * g + 2];
        float4 cw = w4[g];
        PROC_GROUP(g, c0, c1, c2, cw)
    }

    #pragma unroll
    for (int off = 1; off < WAVE; off <<= 1) {
        mnx = fminf(mnx, __shfl_xor(mnx, off));
        mny = fminf(mny, __shfl_xor(mny, off));
        mnz = fminf(mnz, __shfl_xor(mnz, off));
        mxx = fmaxf(mxx, __shfl_xor(mxx, off));
        mxy = fmaxf(mxy, __shfl_xor(mxy, off));
        mxz = fmaxf(mxz, __shfl_xor(mxz, off));
        sw  += __shfl_xor(sw,  off);
        swx += __shfl_xor(swx, off);
        swy += __shfl_xor(swy, off);
        swz += __shfl_xor(swz, off);
    }

    const float diam = fmaxf(mxx - mnx, fmaxf(mxy - mny, mxz - mnz));
    const float wsafe = (sw == 0.f) ? 1.f : sw;
    const float cx = swx / wsafe, cy = swy / wsafe, cz = swz / wsafe;
    const float inv = 1.f / (diam + 0.01f);
    if (lane == 0) diam_out[s] = diam;

    float4* __restrict__ out4 = (float4*)out;

    #define STORE_GROUP(G, R0, R1, R2)                                       \
    {                                                                        \
        const int p = (G) << 2;                                              \
        float4 ra, rb, rc;                                                   \
        ra.x = (R0.x - cx) * inv; ra.y = (R0.y - cy) * inv;                  \
        ra.z = (R0.z - cz) * inv; ra.w = (R0.w - cx) * inv;                  \
        rb.x = (R1.x - cy) * inv; rb.y = (R1.y - cz) * inv;                  \
        rb.z = (R1.z - cx) * inv; rb.w = (R1.w - cy) * inv;                  \
        rc.x = (R2.x - cz) * inv; rc.y = (R2.y - cx) * inv;                  \
        rc.z = (R2.z - cy) * inv; rc.w = (R2.w - cz) * inv;                  \
        if (p >= lo && p + 4 <= hi) {                                        \
            out4[3LL * (G)] = ra; out4[3LL * (G) + 1] = rb;                  \
            out4[3LL * (G) + 2] = rc;                                        \
        } else {                                                             \
            const long long f = 12LL * (G);                                  \
            if (p + 0 >= lo && p + 0 < hi) {                                 \
                out[f + 0] = ra.x; out[f + 1]  = ra.y; out[f + 2]  = ra.z;   \
            }                                                                \
            if (p + 1 >= lo && p + 1 < hi) {                                 \
                out[f + 3] = ra.w; out[f + 4]  = rb.x; out[f + 5]  = rb.y;   \
            }                                                                \
            if (p + 2 >= lo && p + 2 < hi) {                                 \
                out[f + 6] = rb.z; out[f + 7]  = rb.w; out[f + 8]  = rc.x;   \
            }                                                                \
            if (p + 3 >= lo && p + 3 < hi) {                                 \
                out[f + 9] = rc.y; out[f + 10] = rc.z; out[f + 11] = rc.w;   \
            }                                                                \
        }                                                                    \
    }

    STORE_GROUP(ga, a0, a1, a2)   // covers all in-range points; inactive
    STORE_GROUP(gb, b0, b1, b2)   // lanes fail every per-point range test

    // Tail normalize (reload path; never taken for this data).
    for (int g = g0 + 2 * WAVE + lane; g < g1; g += WAVE) {
        float4 c0 = pos4[3LL * g], c1 = pos4[3LL * g + 1], c2 = pos4[3LL * g + 2];
        STORE_GROUP(g, c0, c1, c2)
    }

    #undef STORE_GROUP
    #undef PROC_GROUP
    #undef PROC
}

extern "C" void kernel_launch(void* const* d_in, const int* in_sizes, int n_in,
                              void* d_out, int out_size, void* d_ws, size_t ws_size,
                              hipStream_t stream) {
    const float* pos  = (const float*)d_in[0];
    const void*  idxp = d_in[1];
    const float* w    = (const float*)d_in[2];

    const long long N = (long long)in_sizes[0] / 3;     // 8388608
    const int S = out_size - in_sizes[0];               // 32768

    float* out = (float*)d_out;
    float* diam_out = out + (long long)in_sizes[0];     // tail of d_out

    int* flag  = (int*)d_ws;
    int* start = (int*)((char*)d_ws + 256);

    detect_idx64<<<1, 64, 0, stream>>>((const unsigned int*)idxp, N, flag);

    // One thread per boundary (S+1 of them), 64-thread blocks to spread the
    // latency-bound search chains across all CUs.
    find_bounds_bs<<<(S + 1 + 63) / 64, 64, 0, stream>>>(idxp, flag, start, N, S);

    seg_norm<<<(S + WPB - 1) / WPB, WPB * WAVE, 0, stream>>>(
        pos, w, start, out, diam_out, S);
}

// Round 16
// 53.632 us; speedup vs baseline: 1.6577x; 1.0766x over previous
//
#include <hip/hip_runtime.h>

#define WAVE 64
#define WPB 2    // waves per block (128-thread blocks)

__device__ __forceinline__ int load_idx(const void* __restrict__ p,
                                        long long i, int is64) {
    return is64 ? (int)((const long long*)p)[i] : ((const int*)p)[i];
}

// FUSED dtype-detection + boundary binary search (2-dispatch pipeline).
// Every wave replicates the 64-sample ballot detection (idx may be int32 —
// JAX default — or int64): odd 32-bit words in the upper half are high words
// of values < 2^31 under int64 layout (all zero); under int32 layout they are
// sorted values ~S/2 (nonzero). Then start[t] = lower_bound(idx, t) — one
// independent 23-probe chain per thread, top tree levels L2/L3-hot.
__global__ void find_bounds_bs(const void* __restrict__ idxp,
                               int* __restrict__ start,
                               long long N, int S) {
    const int lane = threadIdx.x & 63;
    long long base = (N / 2) | 1LL;
    long long stride = ((N / 2) / 64) & ~1LL;
    if (stride < 2) stride = 2;
    long long p = base + (long long)lane * stride;
    unsigned int v = (p < N) ? ((const unsigned int*)idxp)[p] : 0u;
    const int is64 = (__ballot(v != 0u) == 0ULL) ? 1 : 0;

    const int t = blockIdx.x * blockDim.x + threadIdx.x;
    if (t > S) return;
    long long lo = 0, hi = N;
    while (lo < hi) {
        long long mid = (lo + hi) >> 1;
        if (load_idx(idxp, mid, is64) < t) lo = mid + 1; else hi = mid;
    }
    start[t] = (int)lo;
}

// One wave per segment (best-measured body, byte-identical to R9/R15).
// Segment <= 512 points (<=2 lane-iterations) in the expected data; both
// iterations peeled statically so all 8 float4 loads issue before any
// dependent use, and the SAME registers feed the normalize phase.
__global__ __launch_bounds__(WPB * WAVE)
void seg_norm(const float* __restrict__ pos,
              const float* __restrict__ w,
              const int* __restrict__ start,
              float* __restrict__ out,
              float* __restrict__ diam_out,
              int S) {
    const int s = blockIdx.x * WPB + (threadIdx.x >> 6);
    if (s >= S) return;
    const int lane = threadIdx.x & 63;

    const int lo = start[s], hi = start[s + 1];
    const int g0 = lo >> 2, g1 = (hi + 3) >> 2;       // 4-point groups

    const float4* __restrict__ pos4 = (const float4*)pos;
    const float4* __restrict__ w4   = (const float4*)w;

    const int ga = g0 + lane;          // iteration 0 group
    const int gb = ga + WAVE;          // iteration 1 group
    const bool va = ga < g1, vb = gb < g1;

    float4 a0 = {0,0,0,0}, a1 = {0,0,0,0}, a2 = {0,0,0,0}, aw = {0,0,0,0};
    float4 b0 = {0,0,0,0}, b1 = {0,0,0,0}, b2 = {0,0,0,0}, bw = {0,0,0,0};
    if (va) {
        a0 = pos4[3LL * ga]; a1 = pos4[3LL * ga + 1]; a2 = pos4[3LL * ga + 2];
        aw = w4[ga];
    }
    if (vb) {
        b0 = pos4[3LL * gb]; b1 = pos4[3LL * gb + 1]; b2 = pos4[3LL * gb + 2];
        bw = w4[gb];
    }

    float mnx = INFINITY,  mny = INFINITY,  mnz = INFINITY;
    float mxx = -INFINITY, mxy = -INFINITY, mxz = -INFINITY;
    float sw = 0.f, swx = 0.f, swy = 0.f, swz = 0.f;

    // p+0: (r0.x,r0.y,r0.z) w.x | p+1: (r0.w,r1.x,r1.y) w.y
    // p+2: (r1.z,r1.w,r2.x) w.z | p+3: (r2.y,r2.z,r2.w) w.w
    #define PROC(PI, X, Y, Z, WV)                                        \
    {                                                                    \
        bool in = ((PI) >= lo) & ((PI) < hi);                            \
        float xv = (X), yv = (Y), zv = (Z);                              \
        float wv = in ? (WV) : 0.f;                                      \
        mnx = fminf(mnx, in ? xv :  INFINITY);                           \
        mxx = fmaxf(mxx, in ? xv : -INFINITY);                           \
        mny = fminf(mny, in ? yv :  INFINITY);                           \
        mxy = fmaxf(mxy, in ? yv : -INFINITY);                           \
        mnz = fminf(mnz, in ? zv :  INFINITY);                           \
        mxz = fmaxf(mxz, in ? zv : -INFINITY);                           \
        sw += wv;                                                        \
        swx = fmaf(wv, xv, swx);                                         \
        swy = fmaf(wv, yv, swy);                                         \
        swz = fmaf(wv, zv, swz);                                         \
    }
    #define PROC_GROUP(G, R0, R1, R2, RW)                                \
    {                                                                    \
        const int p = (G) << 2;                                          \
        PROC(p + 0, R0.x, R0.y, R0.z, RW.x)                              \
        PROC(p + 1, R0.w, R1.x, R1.y, RW.y)                              \
        PROC(p + 2, R1.z, R1.w, R2.x, RW.z)                              \
        PROC(p + 3, R2.y, R2.z, R2.w, RW.w)                              \
    }

    PROC_GROUP(ga, a0, a1, a2, aw)
    PROC_GROUP(gb, b0, b1, b2, bw)

    // Pathological tail (segment > 512 points): never taken for this data.
    for (int g = g0 + 2 * WAVE + lane; g < g1; g += WAVE) {
        float4 c0 = pos4[3LL * g], c1 = pos4[3LL * g + 1], c2 = pos4[3LL * g + 2];
        float4 cw = w4[g];
        PROC_GROUP(g, c0, c1, c2, cw)
    }

    #pragma unroll
    for (int off = 1; off < WAVE; off <<= 1) {
        mnx = fminf(mnx, __shfl_xor(mnx, off));
        mny = fminf(mny, __shfl_xor(mny, off));
        mnz = fminf(mnz, __shfl_xor(mnz, off));
        mxx = fmaxf(mxx, __shfl_xor(mxx, off));
        mxy = fmaxf(mxy, __shfl_xor(mxy, off));
        mxz = fmaxf(mxz, __shfl_xor(mxz, off));
        sw  += __shfl_xor(sw,  off);
        swx += __shfl_xor(swx, off);
        swy += __shfl_xor(swy, off);
        swz += __shfl_xor(swz, off);
    }

    const float diam = fmaxf(mxx - mnx, fmaxf(mxy - mny, mxz - mnz));
    const float wsafe = (sw == 0.f) ? 1.f : sw;
    const float cx = swx / wsafe, cy = swy / wsafe, cz = swz / wsafe;
    const float inv = 1.f / (diam + 0.01f);
    if (lane == 0) diam_out[s] = diam;

    float4* __restrict__ out4 = (float4*)out;

    #define STORE_GROUP(G, R0, R1, R2)                                       \
    {                                                                        \
        const int p = (G) << 2;                                              \
        float4 ra, rb, rc;                                                   \
        ra.x = (R0.x - cx) * inv; ra.y = (R0.y - cy) * inv;                  \
        ra.z = (R0.z - cz) * inv; ra.w = (R0.w - cx) * inv;                  \
        rb.x = (R1.x - cy) * inv; rb.y = (R1.y - cz) * inv;                  \
        rb.z = (R1.z - cx) * inv; rb.w = (R1.w - cy) * inv;                  \
        rc.x = (R2.x - cz) * inv; rc.y = (R2.y - cx) * inv;                  \
        rc.z = (R2.z - cy) * inv; rc.w = (R2.w - cz) * inv;                  \
        if (p >= lo && p + 4 <= hi) {                                        \
            out4[3LL * (G)] = ra; out4[3LL * (G) + 1] = rb;                  \
            out4[3LL * (G) + 2] = rc;                                        \
        } else {                                                             \
            const long long f = 12LL * (G);                                  \
            if (p + 0 >= lo && p + 0 < hi) {                                 \
                out[f + 0] = ra.x; out[f + 1]  = ra.y; out[f + 2]  = ra.z;   \
            }                                                                \
            if (p + 1 >= lo && p + 1 < hi) {                                 \
                out[f + 3] = ra.w; out[f + 4]  = rb.x; out[f + 5]  = rb.y;   \
            }                                                                \
            if (p + 2 >= lo && p + 2 < hi) {                                 \
                out[f + 6] = rb.z; out[f + 7]  = rb.w; out[f + 8]  = rc.x;   \
            }                                                                \
            if (p + 3 >= lo && p + 3 < hi) {                                 \
                out[f + 9] = rc.y; out[f + 10] = rc.z; out[f + 11] = rc.w;   \
            }                                                                \
        }                                                                    \
    }

    STORE_GROUP(ga, a0, a1, a2)   // covers all in-range points; inactive
    STORE_GROUP(gb, b0, b1, b2)   // lanes fail every per-point range test

    // Tail normalize (reload path; never taken for this data).
    for (int g = g0 + 2 * WAVE + lane; g < g1; g += WAVE) {
        float4 c0 = pos4[3LL * g], c1 = pos4[3LL * g + 1], c2 = pos4[3LL * g + 2];
        STORE_GROUP(g, c0, c1, c2)
    }

    #undef STORE_GROUP
    #undef PROC_GROUP
    #undef PROC
}

extern "C" void kernel_launch(void* const* d_in, const int* in_sizes, int n_in,
                              void* d_out, int out_size, void* d_ws, size_t ws_size,
                              hipStream_t stream) {
    const float* pos  = (const float*)d_in[0];
    const void*  idxp = d_in[1];
    const float* w    = (const float*)d_in[2];

    const long long N = (long long)in_sizes[0] / 3;     // 8388608
    const int S = out_size - in_sizes[0];               // 32768

    float* out = (float*)d_out;
    float* diam_out = out + (long long)in_sizes[0];     // tail of d_out

    int* start = (int*)((char*)d_ws + 256);

    // 2 dispatches: detection folded into every find_bounds wave.
    find_bounds_bs<<<(S + 1 + 255) / 256, 256, 0, stream>>>(idxp, start, N, S);

    seg_norm<<<(S + WPB - 1) / WPB, WPB * WAVE, 0, stream>>>(
        pos, w, start, out, diam_out, S);
}